// Round 1
// baseline (855.920 us; speedup 1.0000x reference)
//
#include <hip/hip_runtime.h>
#include <stdint.h>

// Problem constants (ConvLayer_58007828300270)
#define B_   2
#define S_   4096
#define D_   2048
#define DI_  4096
#define M_   (B_ * S_)   // 8192 rows
#define EPS_ 1e-5f

typedef __bf16 bf16x8 __attribute__((ext_vector_type(8)));
typedef float  f32x4  __attribute__((ext_vector_type(4)));
typedef uint16_t u16x8 __attribute__((ext_vector_type(8)));

__device__ __forceinline__ uint16_t f32_to_bf16(float f) {
    uint32_t u = __builtin_bit_cast(uint32_t, f);
    uint32_t r = (u + 0x7fffu + ((u >> 16) & 1u)) >> 16;   // RNE
    return (uint16_t)r;
}
__device__ __forceinline__ float bf16_to_f32(uint16_t h) {
    return __builtin_bit_cast(float, (uint32_t)h << 16);
}

typedef const __attribute__((address_space(1))) uint32_t* gptr_t;
typedef __attribute__((address_space(3))) uint32_t* lptr_t;

// async global->LDS, 16B per lane, dst = wave-uniform base + lane*16
__device__ __forceinline__ void gll16(const void* g, void* l) {
    __builtin_amdgcn_global_load_lds((gptr_t)g, (lptr_t)l, 16, 0, 0);
}

// ---------------------------------------------------------------------------
// Transpose + f32->bf16 convert: W[K][N] f32 -> WT[N][K] bf16. 32x32 tiles.
// ---------------------------------------------------------------------------
__global__ __launch_bounds__(256)
void transpose_bf16_kernel(const float* __restrict__ W, uint16_t* __restrict__ WT,
                           int K, int N) {
    __shared__ float tile[32][33];
    const int nb = N / 32;
    const int tn = blockIdx.x % nb;
    const int tk = blockIdx.x / nb;
    const int tx = threadIdx.x & 31;
    const int ty = threadIdx.x >> 5;          // 0..7
    const int gk = tk * 32, gn = tn * 32;
#pragma unroll
    for (int i = 0; i < 4; i++) {
        int k = ty + i * 8;
        tile[k][tx] = W[(size_t)(gk + k) * N + gn + tx];
    }
    __syncthreads();
#pragma unroll
    for (int i = 0; i < 4; i++) {
        int n = ty + i * 8;
        WT[(size_t)(gn + n) * K + gk + tx] = f32_to_bf16(tile[tx][n]);
    }
}

// ---------------------------------------------------------------------------
// RMSNorm: one block per row, 256 threads x 8 elems. f32 in -> bf16 out.
// ---------------------------------------------------------------------------
__global__ __launch_bounds__(256)
void rmsnorm_kernel(const float* __restrict__ x, const float* __restrict__ w,
                    uint16_t* __restrict__ out) {
    const int row  = blockIdx.x;
    const int tid  = threadIdx.x;
    const int lane = tid & 63, wid = tid >> 6;
    const float* xr = x + (size_t)row * D_;

    f32x4 a = *(const f32x4*)&xr[tid * 8];
    f32x4 b = *(const f32x4*)&xr[tid * 8 + 4];
    float ss = a[0]*a[0] + a[1]*a[1] + a[2]*a[2] + a[3]*a[3]
             + b[0]*b[0] + b[1]*b[1] + b[2]*b[2] + b[3]*b[3];
#pragma unroll
    for (int off = 32; off > 0; off >>= 1) ss += __shfl_xor(ss, off);

    __shared__ float red[4];
    if (lane == 0) red[wid] = ss;
    __syncthreads();
    const float tot = red[0] + red[1] + red[2] + red[3];
    const float scale = rsqrtf(tot * (1.0f / D_) + EPS_);

    f32x4 wa = *(const f32x4*)&w[tid * 8];
    f32x4 wb = *(const f32x4*)&w[tid * 8 + 4];
    u16x8 o;
#pragma unroll
    for (int j = 0; j < 4; j++) o[j]     = f32_to_bf16(a[j] * scale * wa[j]);
#pragma unroll
    for (int j = 0; j < 4; j++) o[j + 4] = f32_to_bf16(b[j] * scale * wb[j]);
    *(u16x8*)&out[(size_t)row * D_ + tid * 8] = o;
}

// ---------------------------------------------------------------------------
// GEMM: C[M][N] = A[M][K] (bf16, row-major) @ BT[N][K]^T (bf16, N-major).
// m97 structure: 128x128 tile, BK=32, 256 thr = 4 waves (2x2 of 64x64),
// global_load_lds width-16 staging, 16x16x32 bf16 MFMA, 4x4 frags/wave.
// EPI: 0 = f32 out + residual add; 1 = bf16 out; 2 = silu -> bf16 out.
// ---------------------------------------------------------------------------
template <int EPI>
__global__ __launch_bounds__(256)
void gemm_bt_kernel(const uint16_t* __restrict__ A, const uint16_t* __restrict__ BT,
                    int M, int N, int K,
                    float* __restrict__ Cf, uint16_t* __restrict__ Cb,
                    const float* __restrict__ resid) {
    const int nbn  = N >> 7;
    const int bm   = blockIdx.x / nbn;
    const int bn   = blockIdx.x % nbn;
    const int brow = bm << 7, bcol = bn << 7;
    const int tid  = threadIdx.x;
    const int wid  = tid >> 6, lane = tid & 63;
    const int wr   = wid >> 1, wc = wid & 1;     // 2x2 wave grid, 64x64 each

    __shared__ uint16_t As[128 * 32];
    __shared__ uint16_t Bs[128 * 32];

    f32x4 acc[4][4];
#pragma unroll
    for (int i = 0; i < 4; i++)
#pragma unroll
        for (int j = 0; j < 4; j++) acc[i][j] = (f32x4){0.f, 0.f, 0.f, 0.f};

    // staging: instruction i (0,1) of wave w covers LDS elems
    // [w*1024 + i*512 + lane*8, +8)  -> row = off/32, kcol = off%32
    const int soff0 = wid * 1024 + lane * 8;
    const int soff1 = soff0 + 512;
    const int r0 = soff0 >> 5, c0 = soff0 & 31;
    const int r1 = soff1 >> 5, c1 = soff1 & 31;
    uint16_t* ldsA0 = &As[wid * 1024];
    uint16_t* ldsA1 = &As[wid * 1024 + 512];
    uint16_t* ldsB0 = &Bs[wid * 1024];
    uint16_t* ldsB1 = &Bs[wid * 1024 + 512];

    const uint16_t* Abase = A  + (size_t)brow * K;
    const uint16_t* Bbase = BT + (size_t)bcol * K;

    // fragment offsets (elems): lane -> row (l&15), k-group ((l>>4)*8)
    const int fr = lane & 15;
    const int fk = (lane >> 4) << 3;
    const int aoff = (wr * 64 + fr) * 32 + fk;
    const int boff = (wc * 64 + fr) * 32 + fk;

    for (int k0 = 0; k0 < K; k0 += 32) {
        gll16(Abase + (size_t)r0 * K + k0 + c0, ldsA0);
        gll16(Abase + (size_t)r1 * K + k0 + c1, ldsA1);
        gll16(Bbase + (size_t)r0 * K + k0 + c0, ldsB0);
        gll16(Bbase + (size_t)r1 * K + k0 + c1, ldsB1);
        __syncthreads();

        bf16x8 af[4], bfv[4];
#pragma unroll
        for (int i = 0; i < 4; i++) af[i]  = *(const bf16x8*)&As[aoff + i * 16 * 32];
#pragma unroll
        for (int j = 0; j < 4; j++) bfv[j] = *(const bf16x8*)&Bs[boff + j * 16 * 32];
#pragma unroll
        for (int i = 0; i < 4; i++)
#pragma unroll
            for (int j = 0; j < 4; j++)
                acc[i][j] = __builtin_amdgcn_mfma_f32_16x16x32_bf16(
                    af[i], bfv[j], acc[i][j], 0, 0, 0);
        __syncthreads();
    }

    // epilogue: C/D layout col = lane&15, row = (lane>>4)*4 + reg
    const int crow0 = brow + wr * 64 + ((lane >> 4) << 2);
    const int ccol0 = bcol + wc * 64 + (lane & 15);
#pragma unroll
    for (int i = 0; i < 4; i++) {
#pragma unroll
        for (int j = 0; j < 4; j++) {
#pragma unroll
            for (int r = 0; r < 4; r++) {
                const size_t idx = (size_t)(crow0 + i * 16 + r) * N + (ccol0 + j * 16);
                const float v = acc[i][j][r];
                if (EPI == 0) {
                    Cf[idx] = v + resid[idx];
                } else if (EPI == 1) {
                    Cb[idx] = f32_to_bf16(v);
                } else {
                    const float s = v / (1.0f + __expf(-v));
                    Cb[idx] = f32_to_bf16(s);
                }
            }
        }
    }
}

// ---------------------------------------------------------------------------
// Causal depthwise conv (K=4) on `up`, multiply by silu-gate (in sg),
// write gated back into sg (in place, element-wise safe).
// 8 channels per thread.
// ---------------------------------------------------------------------------
__global__ __launch_bounds__(256)
void conv_mul_kernel(const uint16_t* __restrict__ up, uint16_t* __restrict__ sg,
                     const float* __restrict__ cw, const float* __restrict__ cb) {
    const size_t gid = (size_t)blockIdx.x * 256 + threadIdx.x;
    const int c8 = (int)(gid % (DI_ / 8));
    const int s  = (int)((gid / (DI_ / 8)) % S_);
    const int b  = (int)(gid / ((size_t)(DI_ / 8) * S_));
    const int c0 = c8 * 8;
    const size_t base = ((size_t)b * S_ + s) * DI_ + c0;

    float accv[8];
#pragma unroll
    for (int j = 0; j < 8; j++) accv[j] = cb[c0 + j];

#pragma unroll
    for (int t = 0; t < 4; t++) {
        const int ss = s - 3 + t;
        if (ss >= 0) {
            const u16x8 uv = *(const u16x8*)&up[((size_t)b * S_ + ss) * DI_ + c0];
#pragma unroll
            for (int j = 0; j < 8; j++)
                accv[j] += bf16_to_f32(uv[j]) * cw[(c0 + j) * 4 + t];
        }
    }
    const u16x8 gv = *(const u16x8*)&sg[base];
    u16x8 o;
#pragma unroll
    for (int j = 0; j < 8; j++)
        o[j] = f32_to_bf16(bf16_to_f32(gv[j]) * accv[j]);
    *(u16x8*)&sg[base] = o;
}

// ---------------------------------------------------------------------------
extern "C" void kernel_launch(void* const* d_in, const int* in_sizes, int n_in,
                              void* d_out, int out_size, void* d_ws, size_t ws_size,
                              hipStream_t stream) {
    const float* x      = (const float*)d_in[0];
    const float* w_norm = (const float*)d_in[1];
    const float* W_up   = (const float*)d_in[2];
    const float* W_gate = (const float*)d_in[3];
    const float* W_down = (const float*)d_in[4];
    const float* conv_w = (const float*)d_in[5];
    const float* conv_b = (const float*)d_in[6];
    float* out = (float*)d_out;

    char* ws = (char*)d_ws;
    uint16_t* normed = (uint16_t*)ws;  ws += (size_t)M_  * D_  * 2;  // 33.5 MB
    uint16_t* WupT   = (uint16_t*)ws;  ws += (size_t)DI_ * D_  * 2;  // 16.8 MB
    uint16_t* WgateT = (uint16_t*)ws;  ws += (size_t)DI_ * D_  * 2;  // 16.8 MB
    uint16_t* WdownT = (uint16_t*)ws;  ws += (size_t)D_  * DI_ * 2;  // 16.8 MB
    uint16_t* up     = (uint16_t*)ws;  ws += (size_t)M_  * DI_ * 2;  // 67 MB
    uint16_t* sg     = (uint16_t*)ws;  ws += (size_t)M_  * DI_ * 2;  // 67 MB

    // weight transposes: W[K][N] -> WT[N][K] bf16
    transpose_bf16_kernel<<<(D_ / 32) * (DI_ / 32), 256, 0, stream>>>(W_up,   WupT,   D_,  DI_);
    transpose_bf16_kernel<<<(D_ / 32) * (DI_ / 32), 256, 0, stream>>>(W_gate, WgateT, D_,  DI_);
    transpose_bf16_kernel<<<(DI_ / 32) * (D_ / 32), 256, 0, stream>>>(W_down, WdownT, DI_, D_);

    rmsnorm_kernel<<<M_, 256, 0, stream>>>(x, w_norm, normed);

    // up = normed @ W_up  (bf16 out)
    gemm_bt_kernel<1><<<(M_ / 128) * (DI_ / 128), 256, 0, stream>>>(
        normed, WupT, M_, DI_, D_, nullptr, up, nullptr);
    // sg = silu(normed @ W_gate)  (bf16 out)
    gemm_bt_kernel<2><<<(M_ / 128) * (DI_ / 128), 256, 0, stream>>>(
        normed, WgateT, M_, DI_, D_, nullptr, sg, nullptr);

    // sg = sg * (causal_dwconv(up) + bias)
    conv_mul_kernel<<<(int)(((size_t)M_ * DI_ / 8) / 256), 256, 0, stream>>>(
        up, sg, conv_w, conv_b);

    // out = x + sg @ W_down  (f32 out, fused residual)
    gemm_bt_kernel<0><<<(M_ / 128) * (D_ / 128), 256, 0, stream>>>(
        sg, WdownT, M_, D_, DI_, out, nullptr, x);
}

// Round 2
// 697.726 us; speedup vs baseline: 1.2267x; 1.2267x over previous
//
#include <hip/hip_runtime.h>
#include <stdint.h>

// Problem constants (ConvLayer_58007828300270)
#define B_   2
#define S_   4096
#define D_   2048
#define DI_  4096
#define M_   (B_ * S_)   // 8192 rows
#define EPS_ 1e-5f

typedef __bf16 bf16x8 __attribute__((ext_vector_type(8)));
typedef float  f32x4  __attribute__((ext_vector_type(4)));
typedef uint16_t u16x8 __attribute__((ext_vector_type(8)));

__device__ __forceinline__ uint16_t f32_to_bf16(float f) {
    uint32_t u = __builtin_bit_cast(uint32_t, f);
    uint32_t r = (u + 0x7fffu + ((u >> 16) & 1u)) >> 16;   // RNE
    return (uint16_t)r;
}
__device__ __forceinline__ float bf16_to_f32(uint16_t h) {
    return __builtin_bit_cast(float, (uint32_t)h << 16);
}

typedef const __attribute__((address_space(1))) uint32_t* gptr_t;
typedef __attribute__((address_space(3))) uint32_t* lptr_t;

// async global->LDS, 16B per lane, dst = wave-uniform base + lane*16
__device__ __forceinline__ void gll16(const void* g, void* l) {
    __builtin_amdgcn_global_load_lds((gptr_t)g, (lptr_t)l, 16, 0, 0);
}

// ---------------------------------------------------------------------------
// Transpose + f32->bf16 convert: W[K][N] f32 -> WT[N][K] bf16. 32x32 tiles.
// ---------------------------------------------------------------------------
__global__ __launch_bounds__(256)
void transpose_bf16_kernel(const float* __restrict__ W, uint16_t* __restrict__ WT,
                           int K, int N) {
    __shared__ float tile[32][33];
    const int nb = N / 32;
    const int tn = blockIdx.x % nb;
    const int tk = blockIdx.x / nb;
    const int tx = threadIdx.x & 31;
    const int ty = threadIdx.x >> 5;          // 0..7
    const int gk = tk * 32, gn = tn * 32;
#pragma unroll
    for (int i = 0; i < 4; i++) {
        int k = ty + i * 8;
        tile[k][tx] = W[(size_t)(gk + k) * N + gn + tx];
    }
    __syncthreads();
#pragma unroll
    for (int i = 0; i < 4; i++) {
        int n = ty + i * 8;
        WT[(size_t)(gn + n) * K + gk + tx] = f32_to_bf16(tile[tx][n]);
    }
}

// ---------------------------------------------------------------------------
// RMSNorm: one block per row, 256 threads x 8 elems. f32 in -> bf16 out.
// ---------------------------------------------------------------------------
__global__ __launch_bounds__(256)
void rmsnorm_kernel(const float* __restrict__ x, const float* __restrict__ w,
                    uint16_t* __restrict__ out) {
    const int row  = blockIdx.x;
    const int tid  = threadIdx.x;
    const int lane = tid & 63, wid = tid >> 6;
    const float* xr = x + (size_t)row * D_;

    f32x4 a = *(const f32x4*)&xr[tid * 8];
    f32x4 b = *(const f32x4*)&xr[tid * 8 + 4];
    float ss = a[0]*a[0] + a[1]*a[1] + a[2]*a[2] + a[3]*a[3]
             + b[0]*b[0] + b[1]*b[1] + b[2]*b[2] + b[3]*b[3];
#pragma unroll
    for (int off = 32; off > 0; off >>= 1) ss += __shfl_xor(ss, off);

    __shared__ float red[4];
    if (lane == 0) red[wid] = ss;
    __syncthreads();
    const float tot = red[0] + red[1] + red[2] + red[3];
    const float scale = rsqrtf(tot * (1.0f / D_) + EPS_);

    f32x4 wa = *(const f32x4*)&w[tid * 8];
    f32x4 wb = *(const f32x4*)&w[tid * 8 + 4];
    u16x8 o;
#pragma unroll
    for (int j = 0; j < 4; j++) o[j]     = f32_to_bf16(a[j] * scale * wa[j]);
#pragma unroll
    for (int j = 0; j < 4; j++) o[j + 4] = f32_to_bf16(b[j] * scale * wb[j]);
    *(u16x8*)&out[(size_t)row * D_ + tid * 8] = o;
}

// ---------------------------------------------------------------------------
// 8-phase 256x256 GEMM: C[M][N] = A[M][K] (bf16 row-major) @ BT[N][K]^T.
// BK=64, 512 thr = 8 waves (2M x 4N), per-wave 128x64 C (8x4 frags 16x16).
// T2 swizzle (byte ^= (row&7)<<4, pre-swizzled gll source + swizzled ds_read),
// T3/T4 4-phase interleave w/ counted vmcnt(4) (never 0), T5 setprio.
// Phase p reads only halves staged >=2 wait-points earlier (hand-traced ledger):
//   stage order per tile t (into buf (t+1)&1): P1:A{q0,q2} P2:B{h0} P3:B{h1} P4:A{q1,q3}
//   waits vmcnt(4) at end of P1,P2,P4.
// B LDS rows permuted rho = h*128 + q*32 + j (r = q*64+h*32+j) so each
// staged 64-row call-pair == one consumed n-half.
// EPI: 0 = f32 out + residual add; 1 = bf16 out; 2 = silu -> bf16 out.
// ---------------------------------------------------------------------------
template <int EPI>
__global__ __launch_bounds__(512, 2)
void gemm8p_kernel(const uint16_t* __restrict__ A, const uint16_t* __restrict__ BT,
                   int M, int N, int K,
                   float* __restrict__ Cf, uint16_t* __restrict__ Cb,
                   const float* __restrict__ resid) {
    __shared__ uint16_t As[2][16384];   // 2 x 32 KiB (256 rows x 64 bf16)
    __shared__ uint16_t Bs[2][16384];

    const int nbn  = N >> 8;
    const int bm   = blockIdx.x / nbn;
    const int bn   = blockIdx.x % nbn;
    const int brow = bm << 8, bcol = bn << 8;
    const int tid  = threadIdx.x;
    const int wid  = tid >> 6, lane = tid & 63;
    const int wr   = wid >> 2, wc = wid & 3;     // 2x4 wave grid
    const int fr   = lane & 15;
    // swizzled k-offset within a 64-elem row (involution on bits 3..5)
    const int kx0 = (((lane >> 4) << 3)) ^ ((lane & 7) << 3);
    const int kx1 = kx0 ^ 32;
    // B fragment LDS rows: rho_n = (n>>1)*128 + wc*32 + (n&1)*16 + fr
    int rhoN[4];
#pragma unroll
    for (int n = 0; n < 4; n++) rhoN[n] = ((n >> 1) << 7) + (wc << 5) + ((n & 1) << 4) + fr;

    // staging source descriptors: call i covers LDS bytes [i*8192, i*8192+8192)
    const uint16_t* ApS[4];
    const uint16_t* BpS[4];
#pragma unroll
    for (int i = 0; i < 4; i++) {
        const int z  = (i << 13) + (wid << 10) + (lane << 4);
        const int zz = z ^ (((z >> 7) & 7) << 4);
        const int row = zz >> 7;           // LDS row = logical A row
        const int kk  = (zz >> 1) & 63;
        ApS[i] = A + (size_t)(brow + row) * K + kk;
        // B: LDS row rho -> logical row r = q*64 + h*32 + j
        const int h = row >> 7, q = (row >> 5) & 3, j = row & 31;
        BpS[i] = BT + (size_t)(bcol + q * 64 + h * 32 + j) * K + kk;
    }

    f32x4 acc[8][4];
#pragma unroll
    for (int i = 0; i < 8; i++)
#pragma unroll
        for (int j = 0; j < 4; j++) acc[i][j] = (f32x4){0.f, 0.f, 0.f, 0.f};

    const int nt = K >> 6;

    // ---- prologue: stage tile 0 fully, drain once ----
#pragma unroll
    for (int i = 0; i < 4; i++) gll16(ApS[i], &As[0][i * 4096 + wid * 512]);
#pragma unroll
    for (int i = 0; i < 4; i++) gll16(BpS[i], &Bs[0][i * 4096 + wid * 512]);
    asm volatile("s_waitcnt vmcnt(0)" ::: "memory");
    __builtin_amdgcn_s_barrier();

    bf16x8 aF[8], bF[8];

    for (int t = 0; t < nt; ++t) {
        const int cur = t & 1, nxt = cur ^ 1;
        const int kn  = (t + 1) << 6;
        const bool pf = (t + 1) < nt;

        // ---------------- P1: read A m-half0 + B n-half0; stage A{q0,q2}
#pragma unroll
        for (int mh = 0; mh < 4; ++mh) {
            const int r = (wr << 7) + (mh << 4) + fr;
            aF[mh * 2 + 0] = *(const bf16x8*)&As[cur][r * 64 + kx0];
            aF[mh * 2 + 1] = *(const bf16x8*)&As[cur][r * 64 + kx1];
        }
#pragma unroll
        for (int n = 0; n < 2; ++n) {
            bF[n * 2 + 0] = *(const bf16x8*)&Bs[cur][rhoN[n] * 64 + kx0];
            bF[n * 2 + 1] = *(const bf16x8*)&Bs[cur][rhoN[n] * 64 + kx1];
        }
        if (pf) {
            gll16(ApS[0] + kn, &As[nxt][0 * 4096 + wid * 512]);
            gll16(ApS[2] + kn, &As[nxt][2 * 4096 + wid * 512]);
        }
        __builtin_amdgcn_s_barrier();
        __builtin_amdgcn_s_setprio(1);
#pragma unroll
        for (int mh = 0; mh < 4; ++mh)
#pragma unroll
            for (int n = 0; n < 2; ++n)
#pragma unroll
                for (int ks = 0; ks < 2; ++ks)
                    acc[mh][n] = __builtin_amdgcn_mfma_f32_16x16x32_bf16(
                        aF[mh * 2 + ks], bF[n * 2 + ks], acc[mh][n], 0, 0, 0);
        __builtin_amdgcn_s_setprio(0);
        asm volatile("s_waitcnt vmcnt(4)" ::: "memory");
        __builtin_amdgcn_s_barrier();

        // ---------------- P2: read B n-half1; stage B{h0}
#pragma unroll
        for (int n = 2; n < 4; ++n) {
            bF[n * 2 + 0] = *(const bf16x8*)&Bs[cur][rhoN[n] * 64 + kx0];
            bF[n * 2 + 1] = *(const bf16x8*)&Bs[cur][rhoN[n] * 64 + kx1];
        }
        if (pf) {
            gll16(BpS[0] + kn, &Bs[nxt][0 * 4096 + wid * 512]);
            gll16(BpS[1] + kn, &Bs[nxt][1 * 4096 + wid * 512]);
        }
        __builtin_amdgcn_s_barrier();
        __builtin_amdgcn_s_setprio(1);
#pragma unroll
        for (int mh = 0; mh < 4; ++mh)
#pragma unroll
            for (int n = 2; n < 4; ++n)
#pragma unroll
                for (int ks = 0; ks < 2; ++ks)
                    acc[mh][n] = __builtin_amdgcn_mfma_f32_16x16x32_bf16(
                        aF[mh * 2 + ks], bF[n * 2 + ks], acc[mh][n], 0, 0, 0);
        __builtin_amdgcn_s_setprio(0);
        asm volatile("s_waitcnt vmcnt(4)" ::: "memory");
        __builtin_amdgcn_s_barrier();

        // ---------------- P3: read A m-half1; stage B{h1}
#pragma unroll
        for (int mh = 0; mh < 4; ++mh) {
            const int r = (wr << 7) + 64 + (mh << 4) + fr;
            aF[mh * 2 + 0] = *(const bf16x8*)&As[cur][r * 64 + kx0];
            aF[mh * 2 + 1] = *(const bf16x8*)&As[cur][r * 64 + kx1];
        }
        if (pf) {
            gll16(BpS[2] + kn, &Bs[nxt][2 * 4096 + wid * 512]);
            gll16(BpS[3] + kn, &Bs[nxt][3 * 4096 + wid * 512]);
        }
        __builtin_amdgcn_s_barrier();
        __builtin_amdgcn_s_setprio(1);
#pragma unroll
        for (int mh = 0; mh < 4; ++mh)
#pragma unroll
            for (int n = 2; n < 4; ++n)
#pragma unroll
                for (int ks = 0; ks < 2; ++ks)
                    acc[4 + mh][n] = __builtin_amdgcn_mfma_f32_16x16x32_bf16(
                        aF[mh * 2 + ks], bF[n * 2 + ks], acc[4 + mh][n], 0, 0, 0);
        __builtin_amdgcn_s_setprio(0);
        __builtin_amdgcn_s_barrier();

        // ---------------- P4: no reads; stage A{q1,q3}
        if (pf) {
            gll16(ApS[1] + kn, &As[nxt][1 * 4096 + wid * 512]);
            gll16(ApS[3] + kn, &As[nxt][3 * 4096 + wid * 512]);
        }
        __builtin_amdgcn_s_barrier();
        __builtin_amdgcn_s_setprio(1);
#pragma unroll
        for (int mh = 0; mh < 4; ++mh)
#pragma unroll
            for (int n = 0; n < 2; ++n)
#pragma unroll
                for (int ks = 0; ks < 2; ++ks)
                    acc[4 + mh][n] = __builtin_amdgcn_mfma_f32_16x16x32_bf16(
                        aF[mh * 2 + ks], bF[n * 2 + ks], acc[4 + mh][n], 0, 0, 0);
        __builtin_amdgcn_s_setprio(0);
        asm volatile("s_waitcnt vmcnt(4)" ::: "memory");
        __builtin_amdgcn_s_barrier();
    }

    // epilogue: C/D layout col = lane&15, row = (lane>>4)*4 + reg
    const int r0 = (lane >> 4) << 2;
#pragma unroll
    for (int m = 0; m < 8; ++m) {
        const int row = brow + (wr << 7) + ((m >> 2) << 6) + ((m & 3) << 4) + r0;
#pragma unroll
        for (int n = 0; n < 4; ++n) {
            const int col = bcol + (wc << 6) + (n << 4) + fr;
#pragma unroll
            for (int r = 0; r < 4; ++r) {
                const size_t idx = (size_t)(row + r) * N + col;
                const float v = acc[m][n][r];
                if (EPI == 0) {
                    Cf[idx] = v + resid[idx];
                } else if (EPI == 1) {
                    Cb[idx] = f32_to_bf16(v);
                } else {
                    const float s = v / (1.0f + __expf(-v));
                    Cb[idx] = f32_to_bf16(s);
                }
            }
        }
    }
}

// ---------------------------------------------------------------------------
// Causal depthwise conv (K=4) on `up`, multiply by silu-gate (in sg),
// write gated back into sg (in place, element-wise safe).
// ---------------------------------------------------------------------------
__global__ __launch_bounds__(256)
void conv_mul_kernel(const uint16_t* __restrict__ up, uint16_t* __restrict__ sg,
                     const float* __restrict__ cw, const float* __restrict__ cb) {
    const size_t gid = (size_t)blockIdx.x * 256 + threadIdx.x;
    const int c8 = (int)(gid % (DI_ / 8));
    const int s  = (int)((gid / (DI_ / 8)) % S_);
    const int b  = (int)(gid / ((size_t)(DI_ / 8) * S_));
    const int c0 = c8 * 8;
    const size_t base = ((size_t)b * S_ + s) * DI_ + c0;

    float accv[8];
#pragma unroll
    for (int j = 0; j < 8; j++) accv[j] = cb[c0 + j];

#pragma unroll
    for (int t = 0; t < 4; t++) {
        const int ss = s - 3 + t;
        if (ss >= 0) {
            const u16x8 uv = *(const u16x8*)&up[((size_t)b * S_ + ss) * DI_ + c0];
#pragma unroll
            for (int j = 0; j < 8; j++)
                accv[j] += bf16_to_f32(uv[j]) * cw[(c0 + j) * 4 + t];
        }
    }
    const u16x8 gv = *(const u16x8*)&sg[base];
    u16x8 o;
#pragma unroll
    for (int j = 0; j < 8; j++)
        o[j] = f32_to_bf16(bf16_to_f32(gv[j]) * accv[j]);
    *(u16x8*)&sg[base] = o;
}

// ---------------------------------------------------------------------------
extern "C" void kernel_launch(void* const* d_in, const int* in_sizes, int n_in,
                              void* d_out, int out_size, void* d_ws, size_t ws_size,
                              hipStream_t stream) {
    const float* x      = (const float*)d_in[0];
    const float* w_norm = (const float*)d_in[1];
    const float* W_up   = (const float*)d_in[2];
    const float* W_gate = (const float*)d_in[3];
    const float* W_down = (const float*)d_in[4];
    const float* conv_w = (const float*)d_in[5];
    const float* conv_b = (const float*)d_in[6];
    float* out = (float*)d_out;

    char* ws = (char*)d_ws;
    uint16_t* normed = (uint16_t*)ws;  ws += (size_t)M_  * D_  * 2;  // 33.5 MB
    uint16_t* WupT   = (uint16_t*)ws;  ws += (size_t)DI_ * D_  * 2;  // 16.8 MB
    uint16_t* WgateT = (uint16_t*)ws;  ws += (size_t)DI_ * D_  * 2;  // 16.8 MB
    uint16_t* WdownT = (uint16_t*)ws;  ws += (size_t)D_  * DI_ * 2;  // 16.8 MB
    uint16_t* up     = (uint16_t*)ws;  ws += (size_t)M_  * DI_ * 2;  // 67 MB
    uint16_t* sg     = (uint16_t*)ws;  ws += (size_t)M_  * DI_ * 2;  // 67 MB

    // weight transposes: W[K][N] -> WT[N][K] bf16
    transpose_bf16_kernel<<<(D_ / 32) * (DI_ / 32), 256, 0, stream>>>(W_up,   WupT,   D_,  DI_);
    transpose_bf16_kernel<<<(D_ / 32) * (DI_ / 32), 256, 0, stream>>>(W_gate, WgateT, D_,  DI_);
    transpose_bf16_kernel<<<(DI_ / 32) * (D_ / 32), 256, 0, stream>>>(W_down, WdownT, DI_, D_);

    rmsnorm_kernel<<<M_, 256, 0, stream>>>(x, w_norm, normed);

    // up = normed @ W_up  (bf16 out)
    gemm8p_kernel<1><<<(M_ / 256) * (DI_ / 256), 512, 0, stream>>>(
        normed, WupT, M_, DI_, D_, nullptr, up, nullptr);
    // sg = silu(normed @ W_gate)  (bf16 out)
    gemm8p_kernel<2><<<(M_ / 256) * (DI_ / 256), 512, 0, stream>>>(
        normed, WgateT, M_, DI_, D_, nullptr, sg, nullptr);

    // sg = sg * (causal_dwconv(up) + bias)
    conv_mul_kernel<<<(int)(((size_t)M_ * DI_ / 8) / 256), 256, 0, stream>>>(
        up, sg, conv_w, conv_b);

    // out = x + sg @ W_down  (f32 out, fused residual)
    gemm8p_kernel<0><<<(M_ / 256) * (D_ / 256), 512, 0, stream>>>(
        sg, WdownT, M_, D_, DI_, out, nullptr, x);
}

// Round 4
// 501.961 us; speedup vs baseline: 1.7052x; 1.3900x over previous
//
#include <hip/hip_runtime.h>
#include <stdint.h>

// Problem constants (ConvLayer_58007828300270)
#define B_   2
#define S_   4096
#define D_   2048
#define DI_  4096
#define M_   (B_ * S_)   // 8192 rows
#define EPS_ 1e-5f
#define SCH_ 8           // conv: s-rows per thread

typedef __bf16 bf16x8 __attribute__((ext_vector_type(8)));
typedef float  f32x4  __attribute__((ext_vector_type(4)));
typedef uint16_t u16x8 __attribute__((ext_vector_type(8)));

__device__ __forceinline__ uint16_t f32_to_bf16(float f) {
    uint32_t u = __builtin_bit_cast(uint32_t, f);
    uint32_t r = (u + 0x7fffu + ((u >> 16) & 1u)) >> 16;   // RNE
    return (uint16_t)r;
}
__device__ __forceinline__ float bf16_to_f32(uint16_t h) {
    return __builtin_bit_cast(float, (uint32_t)h << 16);
}

typedef const __attribute__((address_space(1))) uint32_t* gptr_t;
typedef __attribute__((address_space(3))) uint32_t* lptr_t;

// async global->LDS, 16B per lane, dst = wave-uniform base + lane*16
__device__ __forceinline__ void gll16(const void* g, void* l) {
    __builtin_amdgcn_global_load_lds((gptr_t)g, (lptr_t)l, 16, 0, 0);
}

// ---------------------------------------------------------------------------
// Transpose + f32->bf16 convert: W[K][N] f32 -> WT[N][K] bf16. 32x32 tiles.
// ---------------------------------------------------------------------------
__global__ __launch_bounds__(256)
void transpose_bf16_kernel(const float* __restrict__ W, uint16_t* __restrict__ WT,
                           int K, int N) {
    __shared__ float tile[32][33];
    const int nb = N / 32;
    const int tn = blockIdx.x % nb;
    const int tk = blockIdx.x / nb;
    const int tx = threadIdx.x & 31;
    const int ty = threadIdx.x >> 5;          // 0..7
    const int gk = tk * 32, gn = tn * 32;
#pragma unroll
    for (int i = 0; i < 4; i++) {
        int k = ty + i * 8;
        tile[k][tx] = W[(size_t)(gk + k) * N + gn + tx];
    }
    __syncthreads();
#pragma unroll
    for (int i = 0; i < 4; i++) {
        int n = ty + i * 8;
        WT[(size_t)(gn + n) * K + gk + tx] = f32_to_bf16(tile[tx][n]);
    }
}

// ---------------------------------------------------------------------------
// RMSNorm: one block per row, 256 threads x 8 elems. f32 in -> bf16 out.
// ---------------------------------------------------------------------------
__global__ __launch_bounds__(256)
void rmsnorm_kernel(const float* __restrict__ x, const float* __restrict__ w,
                    uint16_t* __restrict__ out) {
    const int row  = blockIdx.x;
    const int tid  = threadIdx.x;
    const int lane = tid & 63, wid = tid >> 6;
    const float* xr = x + (size_t)row * D_;

    f32x4 a = *(const f32x4*)&xr[tid * 8];
    f32x4 b = *(const f32x4*)&xr[tid * 8 + 4];
    float ss = a[0]*a[0] + a[1]*a[1] + a[2]*a[2] + a[3]*a[3]
             + b[0]*b[0] + b[1]*b[1] + b[2]*b[2] + b[3]*b[3];
#pragma unroll
    for (int off = 32; off > 0; off >>= 1) ss += __shfl_xor(ss, off);

    __shared__ float red[4];
    if (lane == 0) red[wid] = ss;
    __syncthreads();
    const float tot = red[0] + red[1] + red[2] + red[3];
    const float scale = rsqrtf(tot * (1.0f / D_) + EPS_);

    f32x4 wa = *(const f32x4*)&w[tid * 8];
    f32x4 wb = *(const f32x4*)&w[tid * 8 + 4];
    u16x8 o;
#pragma unroll
    for (int j = 0; j < 4; j++) o[j]     = f32_to_bf16(a[j] * scale * wa[j]);
#pragma unroll
    for (int j = 0; j < 4; j++) o[j + 4] = f32_to_bf16(b[j] * scale * wb[j]);
    *(u16x8*)&out[(size_t)row * D_ + tid * 8] = o;
}

// ---------------------------------------------------------------------------
// 8-phase 256x256 GEMM: C[M][N] = A[M][K] (bf16 row-major) @ BT[N][K]^T.
// BK=64, 512 thr = 8 waves (2M x 4N), per-wave 128x64 C (8x4 frags 16x16).
// T1 XCD swizzle, T2 swizzle (byte ^= (row&7)<<4, pre-swizzled gll source +
// swizzled ds_read), T3/T4 4-phase interleave w/ counted vmcnt(4), T5 setprio.
// EPI: 0 = f32 out + residual add
//      3 = fused up/gate: col<DI_ -> Cb (bf16), col>=DI_ -> silu -> Cb2.
// ---------------------------------------------------------------------------
template <int EPI>
__global__ __launch_bounds__(512, 2)
void gemm8p_kernel(const uint16_t* __restrict__ A, const uint16_t* __restrict__ BT,
                   int M, int N, int K,
                   float* __restrict__ Cf, uint16_t* __restrict__ Cb,
                   uint16_t* __restrict__ Cb2, const float* __restrict__ resid) {
    __shared__ uint16_t As[2][16384];   // 2 x 32 KiB (256 rows x 64 bf16)
    __shared__ uint16_t Bs[2][16384];

    // T1: bijective XCD swizzle (grid % 8 == 0 for all our launches)
    const int nwg = gridDim.x;
    const int cpx = nwg >> 3;
    const int bid = blockIdx.x;
    const int swz = (bid & 7) * cpx + (bid >> 3);

    const int nbn  = N >> 8;
    const int bm   = swz / nbn;
    const int bn   = swz % nbn;
    const int brow = bm << 8, bcol = bn << 8;
    const int tid  = threadIdx.x;
    const int wid  = tid >> 6, lane = tid & 63;
    const int wr   = wid >> 2, wc = wid & 3;     // 2x4 wave grid
    const int fr   = lane & 15;
    // swizzled k-offset within a 64-elem row (involution on bits 3..5)
    const int kx0 = (((lane >> 4) << 3)) ^ ((lane & 7) << 3);
    const int kx1 = kx0 ^ 32;
    // B fragment LDS rows: rho_n = (n>>1)*128 + wc*32 + (n&1)*16 + fr
    int rhoN[4];
#pragma unroll
    for (int n = 0; n < 4; n++) rhoN[n] = ((n >> 1) << 7) + (wc << 5) + ((n & 1) << 4) + fr;

    // staging source descriptors: call i covers LDS bytes [i*8192, i*8192+8192)
    const uint16_t* ApS[4];
    const uint16_t* BpS[4];
#pragma unroll
    for (int i = 0; i < 4; i++) {
        const int z  = (i << 13) + (wid << 10) + (lane << 4);
        const int zz = z ^ (((z >> 7) & 7) << 4);
        const int row = zz >> 7;           // LDS row = logical A row
        const int kk  = (zz >> 1) & 63;
        ApS[i] = A + (size_t)(brow + row) * K + kk;
        // B: LDS row rho -> logical row r = q*64 + h*32 + j
        const int h = row >> 7, q = (row >> 5) & 3, j = row & 31;
        BpS[i] = BT + (size_t)(bcol + q * 64 + h * 32 + j) * K + kk;
    }

    f32x4 acc[8][4];
#pragma unroll
    for (int i = 0; i < 8; i++)
#pragma unroll
        for (int j = 0; j < 4; j++) acc[i][j] = (f32x4){0.f, 0.f, 0.f, 0.f};

    const int nt = K >> 6;

    // ---- prologue: stage tile 0 fully, drain once ----
#pragma unroll
    for (int i = 0; i < 4; i++) gll16(ApS[i], &As[0][i * 4096 + wid * 512]);
#pragma unroll
    for (int i = 0; i < 4; i++) gll16(BpS[i], &Bs[0][i * 4096 + wid * 512]);
    asm volatile("s_waitcnt vmcnt(0)" ::: "memory");
    __builtin_amdgcn_s_barrier();

    bf16x8 aF[8], bF[8];

    for (int t = 0; t < nt; ++t) {
        const int cur = t & 1, nxt = cur ^ 1;
        const int kn  = (t + 1) << 6;
        const bool pf = (t + 1) < nt;

        // ---------------- P1: read A m-half0 + B n-half0; stage A{q0,q2}
#pragma unroll
        for (int mh = 0; mh < 4; ++mh) {
            const int r = (wr << 7) + (mh << 4) + fr;
            aF[mh * 2 + 0] = *(const bf16x8*)&As[cur][r * 64 + kx0];
            aF[mh * 2 + 1] = *(const bf16x8*)&As[cur][r * 64 + kx1];
        }
#pragma unroll
        for (int n = 0; n < 2; ++n) {
            bF[n * 2 + 0] = *(const bf16x8*)&Bs[cur][rhoN[n] * 64 + kx0];
            bF[n * 2 + 1] = *(const bf16x8*)&Bs[cur][rhoN[n] * 64 + kx1];
        }
        if (pf) {
            gll16(ApS[0] + kn, &As[nxt][0 * 4096 + wid * 512]);
            gll16(ApS[2] + kn, &As[nxt][2 * 4096 + wid * 512]);
        }
        __builtin_amdgcn_s_barrier();
        __builtin_amdgcn_s_setprio(1);
#pragma unroll
        for (int mh = 0; mh < 4; ++mh)
#pragma unroll
            for (int n = 0; n < 2; ++n)
#pragma unroll
                for (int ks = 0; ks < 2; ++ks)
                    acc[mh][n] = __builtin_amdgcn_mfma_f32_16x16x32_bf16(
                        aF[mh * 2 + ks], bF[n * 2 + ks], acc[mh][n], 0, 0, 0);
        __builtin_amdgcn_s_setprio(0);
        asm volatile("s_waitcnt vmcnt(4)" ::: "memory");
        __builtin_amdgcn_s_barrier();

        // ---------------- P2: read B n-half1; stage B{h0}
#pragma unroll
        for (int n = 2; n < 4; ++n) {
            bF[n * 2 + 0] = *(const bf16x8*)&Bs[cur][rhoN[n] * 64 + kx0];
            bF[n * 2 + 1] = *(const bf16x8*)&Bs[cur][rhoN[n] * 64 + kx1];
        }
        if (pf) {
            gll16(BpS[0] + kn, &Bs[nxt][0 * 4096 + wid * 512]);
            gll16(BpS[1] + kn, &Bs[nxt][1 * 4096 + wid * 512]);
        }
        __builtin_amdgcn_s_barrier();
        __builtin_amdgcn_s_setprio(1);
#pragma unroll
        for (int mh = 0; mh < 4; ++mh)
#pragma unroll
            for (int n = 2; n < 4; ++n)
#pragma unroll
                for (int ks = 0; ks < 2; ++ks)
                    acc[mh][n] = __builtin_amdgcn_mfma_f32_16x16x32_bf16(
                        aF[mh * 2 + ks], bF[n * 2 + ks], acc[mh][n], 0, 0, 0);
        __builtin_amdgcn_s_setprio(0);
        asm volatile("s_waitcnt vmcnt(4)" ::: "memory");
        __builtin_amdgcn_s_barrier();

        // ---------------- P3: read A m-half1; stage B{h1}
#pragma unroll
        for (int mh = 0; mh < 4; ++mh) {
            const int r = (wr << 7) + 64 + (mh << 4) + fr;
            aF[mh * 2 + 0] = *(const bf16x8*)&As[cur][r * 64 + kx0];
            aF[mh * 2 + 1] = *(const bf16x8*)&As[cur][r * 64 + kx1];
        }
        if (pf) {
            gll16(BpS[2] + kn, &Bs[nxt][2 * 4096 + wid * 512]);
            gll16(BpS[3] + kn, &Bs[nxt][3 * 4096 + wid * 512]);
        }
        __builtin_amdgcn_s_barrier();
        __builtin_amdgcn_s_setprio(1);
#pragma unroll
        for (int mh = 0; mh < 4; ++mh)
#pragma unroll
            for (int n = 2; n < 4; ++n)
#pragma unroll
                for (int ks = 0; ks < 2; ++ks)
                    acc[4 + mh][n] = __builtin_amdgcn_mfma_f32_16x16x32_bf16(
                        aF[mh * 2 + ks], bF[n * 2 + ks], acc[4 + mh][n], 0, 0, 0);
        __builtin_amdgcn_s_setprio(0);
        __builtin_amdgcn_s_barrier();

        // ---------------- P4: no reads; stage A{q1,q3}
        if (pf) {
            gll16(ApS[1] + kn, &As[nxt][1 * 4096 + wid * 512]);
            gll16(ApS[3] + kn, &As[nxt][3 * 4096 + wid * 512]);
        }
        __builtin_amdgcn_s_barrier();
        __builtin_amdgcn_s_setprio(1);
#pragma unroll
        for (int mh = 0; mh < 4; ++mh)
#pragma unroll
            for (int n = 0; n < 2; ++n)
#pragma unroll
                for (int ks = 0; ks < 2; ++ks)
                    acc[4 + mh][n] = __builtin_amdgcn_mfma_f32_16x16x32_bf16(
                        aF[mh * 2 + ks], bF[n * 2 + ks], acc[4 + mh][n], 0, 0, 0);
        __builtin_amdgcn_s_setprio(0);
        asm volatile("s_waitcnt vmcnt(4)" ::: "memory");
        __builtin_amdgcn_s_barrier();
    }

    // epilogue: C/D layout col = lane&15, row = (lane>>4)*4 + reg
    const int r0 = (lane >> 4) << 2;
    const bool upHalf = (bcol < DI_);   // block-uniform for EPI==3 (DI_%256==0)
#pragma unroll
    for (int m = 0; m < 8; ++m) {
        const int row = brow + (wr << 7) + ((m >> 2) << 6) + ((m & 3) << 4) + r0;
#pragma unroll
        for (int n = 0; n < 4; ++n) {
            const int col = bcol + (wc << 6) + (n << 4) + fr;
#pragma unroll
            for (int r = 0; r < 4; ++r) {
                const float v = acc[m][n][r];
                if (EPI == 0) {
                    const size_t idx = (size_t)(row + r) * N + col;
                    Cf[idx] = v + resid[idx];
                } else {  // EPI == 3: fused up/gate routing
                    if (upHalf) {
                        Cb[(size_t)(row + r) * DI_ + col] = f32_to_bf16(v);
                    } else {
                        const float s = v / (1.0f + __expf(-v));
                        Cb2[(size_t)(row + r) * DI_ + (col - DI_)] = f32_to_bf16(s);
                    }
                }
            }
        }
    }
}

// ---------------------------------------------------------------------------
// Causal depthwise conv (K=4) on `up`, multiply by silu-gate (in sg),
// write gated back into sg (in place, element-wise safe).
// Each thread: 8 channels x SCH_ consecutive s-rows; weights in registers,
// causal window slides in registers (3 boundary loads per chunk).
// ---------------------------------------------------------------------------
__global__ __launch_bounds__(256)
void conv_mul_kernel(const uint16_t* __restrict__ up, uint16_t* __restrict__ sg,
                     const float* __restrict__ cw, const float* __restrict__ cb) {
    const size_t gid = (size_t)blockIdx.x * 256 + threadIdx.x;
    const int c8 = (int)(gid % (DI_ / 8));                 // channel group, fastest
    const int sc = (int)((gid / (DI_ / 8)) % (S_ / SCH_)); // s-chunk
    const int b  = (int)(gid / ((size_t)(DI_ / 8) * (S_ / SCH_)));
    const int c0 = c8 * 8;
    const int s0 = sc * SCH_;

    // weights: cw[(c0+j)*4 + t] -> 32 contiguous floats at cw + c0*4
    f32x4 wv[8];
#pragma unroll
    for (int j = 0; j < 8; j++) wv[j] = *(const f32x4*)&cw[(c0 + j) * 4];
    const f32x4 b0 = *(const f32x4*)&cb[c0];
    const f32x4 b1 = *(const f32x4*)&cb[c0 + 4];

    const uint16_t* upb = up + (size_t)b * S_ * DI_ + c0;
    uint16_t*       sgb = sg + (size_t)b * S_ * DI_ + c0;

    // sliding window: rows s0-3, s0-2, s0-1 (zeros below row 0)
    u16x8 win[3];
#pragma unroll
    for (int i = 0; i < 3; i++) {
        const int ss = s0 - 3 + i;
        if (ss >= 0) {
            win[i] = *(const u16x8*)&upb[(size_t)ss * DI_];
        } else {
#pragma unroll
            for (int j = 0; j < 8; j++) win[i][j] = 0;
        }
    }

#pragma unroll
    for (int st = 0; st < SCH_; ++st) {
        const size_t roff = (size_t)(s0 + st) * DI_;
        const u16x8 curv = *(const u16x8*)&upb[roff];
        const u16x8 gv   = *(const u16x8*)&sgb[roff];
        u16x8 o;
#pragma unroll
        for (int j = 0; j < 8; j++) {
            const float bias = (j < 4) ? b0[j] : b1[j - 4];
            const float a = bias
                + bf16_to_f32(win[0][j]) * wv[j][0]
                + bf16_to_f32(win[1][j]) * wv[j][1]
                + bf16_to_f32(win[2][j]) * wv[j][2]
                + bf16_to_f32(curv[j])   * wv[j][3];
            o[j] = f32_to_bf16(bf16_to_f32(gv[j]) * a);
        }
        *(u16x8*)&sgb[roff] = o;
        win[0] = win[1]; win[1] = win[2]; win[2] = curv;
    }
}

// ---------------------------------------------------------------------------
extern "C" void kernel_launch(void* const* d_in, const int* in_sizes, int n_in,
                              void* d_out, int out_size, void* d_ws, size_t ws_size,
                              hipStream_t stream) {
    const float* x      = (const float*)d_in[0];
    const float* w_norm = (const float*)d_in[1];
    const float* W_up   = (const float*)d_in[2];
    const float* W_gate = (const float*)d_in[3];
    const float* W_down = (const float*)d_in[4];
    const float* conv_w = (const float*)d_in[5];
    const float* conv_b = (const float*)d_in[6];
    float* out = (float*)d_out;

    char* ws = (char*)d_ws;
    uint16_t* normed = (uint16_t*)ws;  ws += (size_t)M_  * D_  * 2;  // 33.5 MB
    uint16_t* WupT   = (uint16_t*)ws;  ws += (size_t)DI_ * D_  * 2;  // 16.8 MB  (adjacent:
    uint16_t* WgateT = (uint16_t*)ws;  ws += (size_t)DI_ * D_  * 2;  // 16.8 MB   fused B^T [8192][2048])
    uint16_t* WdownT = (uint16_t*)ws;  ws += (size_t)D_  * DI_ * 2;  // 16.8 MB
    uint16_t* up     = (uint16_t*)ws;  ws += (size_t)M_  * DI_ * 2;  // 67 MB
    uint16_t* sg     = (uint16_t*)ws;  ws += (size_t)M_  * DI_ * 2;  // 67 MB

    // weight transposes: W[K][N] -> WT[N][K] bf16
    transpose_bf16_kernel<<<(D_ / 32) * (DI_ / 32), 256, 0, stream>>>(W_up,   WupT,   D_,  DI_);
    transpose_bf16_kernel<<<(D_ / 32) * (DI_ / 32), 256, 0, stream>>>(W_gate, WgateT, D_,  DI_);
    transpose_bf16_kernel<<<(DI_ / 32) * (D_ / 32), 256, 0, stream>>>(W_down, WdownT, DI_, D_);

    rmsnorm_kernel<<<M_, 256, 0, stream>>>(x, w_norm, normed);

    // fused: [up | silu(gate)] = normed @ [W_up | W_gate]   (N = 2*DI_ = 8192)
    gemm8p_kernel<3><<<(M_ / 256) * ((2 * DI_) / 256), 512, 0, stream>>>(
        normed, WupT, M_, 2 * DI_, D_, nullptr, up, sg, nullptr);

    // sg = sg * (causal_dwconv(up) + bias)
    conv_mul_kernel<<<(int)(((size_t)B_ * (S_ / SCH_) * (DI_ / 8)) / 256), 256, 0, stream>>>(
        up, sg, conv_w, conv_b);

    // out = x + sg @ W_down  (f32 out, fused residual)
    gemm8p_kernel<0><<<(M_ / 256) * (D_ / 256), 512, 0, stream>>>(
        sg, WdownT, M_, D_, DI_, out, nullptr, nullptr, x);
}